// Round 4
// baseline (1137.607 us; speedup 1.0000x reference)
//
#include <hip/hip_runtime.h>
#include <hip/hip_bf16.h>

#define N_TOK 32768
#define DIM   512
#define NE    2048

// d_out is FLOAT32, outputs concatenated flat in return order:
// z_q_st [N_TOK*DIM] | indices [N_TOK] | loss [1] | perplexity [1]
#define IDX_OFF  (N_TOK * DIM)        // 16777216
#define LOSS_OFF (IDX_OFF + N_TOK)    // 16809984
#define PERP_OFF (LOSS_OFF + 1)

#define KB(x) ((size_t)(x) << 10)

__device__ inline unsigned short f2bf(float f) {
  unsigned int x = __float_as_uint(f);
  x = x + 0x7fffu + ((x >> 16) & 1u);   // round-to-nearest-even
  return (unsigned short)(x >> 16);
}
// fp32 value rounded through bf16
__device__ inline float bfround(float f) {
  return __uint_as_float((unsigned int)f2bf(f) << 16);
}

__global__ void init_kernel(int* counts, float* loss) {
  int t = threadIdx.x;
  for (int i = t; i < NE; i += 256) counts[i] = 0;
  if (t == 0) *loss = 0.f;
}

// Replicate np.sum(x*x, axis=1) for n=512 fp32 rows, numpy pairwise + AVX512:
// sum = (L0+L1)+(L2+L3); leaf128: lane l in 0..15 computes
//   v[l] = ((q[l]+q[l+16]) + (q[l+32]+q[l+48])) + ((q[l+64]+q[l+80]) + (q[l+96]+q[l+112]))
// (q = fl(x^2)), then halving tree over lanes: 8,4,2,1.
// 16 lanes per row; 4 rows per wave; 16 rows per 256-block.
__global__ __launch_bounds__(256) void npsum_sq(const float* __restrict__ x,
                                                float* __restrict__ out, int nrows) {
#pragma clang fp contract(off)
  int wave = threadIdx.x >> 6;
  int lane = threadIdx.x & 63;
  int grp = lane >> 4, l = lane & 15;
  int row = blockIdx.x * 16 + wave * 4 + grp;
  if (row >= nrows) return;
  const float* a = x + (size_t)row * DIM;
  float L[4];
  #pragma unroll
  for (int b = 0; b < 4; ++b) {
    const float* p = a + b * 128 + l;
    float q[8];
    #pragma unroll
    for (int j = 0; j < 8; ++j) {
      float t = p[16 * j];
      float s = t * t;                    // fl(x^2), single rounding
      asm volatile("" : "+v"(s));         // block any mul+add contraction
      q[j] = s;
    }
    float v = ((q[0] + q[1]) + (q[2] + q[3])) + ((q[4] + q[5]) + (q[6] + q[7]));
    v += __shfl_xor(v, 8);   // halving tree (commutative adds, order-safe)
    v += __shfl_xor(v, 4);
    v += __shfl_xor(v, 2);
    v += __shfl_xor(v, 1);
    L[b] = v;
  }
  if (l == 0) out[row] = (L[0] + L[1]) + (L[2] + L[3]);
}

// One block = 64 tokens x ALL 2048 codes (8 groups of 256), 256 threads.
// d_ij = fl( fl(zsum_i + esum_j) - 2*dot_ij ), argmin with FIRST-index ties
// (replicates np fp32 semantics; dot in accurate sequential fp32).
__global__ __launch_bounds__(256) void dist_topk(
    const float* __restrict__ z, const float* __restrict__ e,
    const float* __restrict__ zsum, const float* __restrict__ esum,
    int* __restrict__ idx_final, int* __restrict__ counts,
    float* __restrict__ out) {
  __shared__ float zs[16][64];    // [k][token]
  __shared__ float es[16][256];   // [k][code]
  const int tid = threadIdx.x;
  const int tb = blockIdx.x;
  const int tx = tid & 31, ty = tid >> 5;
  const int sr = tid >> 2, sc = tid & 3;

  float bv1[8]; int bi1[8];
  #pragma unroll
  for (int i = 0; i < 8; ++i) { bv1[i] = 3.402823466e38f; bi1[i] = 0x7fffffff; }

  float zsr[8];
  #pragma unroll
  for (int i = 0; i < 8; ++i) zsr[i] = zsum[tb * 64 + ty * 8 + i];

  const float* zp = z + (size_t)(tb * 64 + sr) * DIM + sc * 4;

  for (int cg = 0; cg < 8; ++cg) {
    float acc[8][8];
    #pragma unroll
    for (int i = 0; i < 8; ++i)
      #pragma unroll
      for (int j = 0; j < 8; ++j) acc[i][j] = 0.f;

    const float* ep = e + (size_t)(cg * 256 + sr) * DIM + sc * 4;

    for (int kt = 0; kt < DIM / 16; ++kt) {
      float4 zv  = *(const float4*)(zp + kt * 16);
      float4 ev0 = *(const float4*)(ep + kt * 16);
      float4 ev1 = *(const float4*)(ep + (size_t) 64 * DIM + kt * 16);
      float4 ev2 = *(const float4*)(ep + (size_t)128 * DIM + kt * 16);
      float4 ev3 = *(const float4*)(ep + (size_t)192 * DIM + kt * 16);
      __syncthreads();
      zs[sc*4+0][sr] = zv.x; zs[sc*4+1][sr] = zv.y;
      zs[sc*4+2][sr] = zv.z; zs[sc*4+3][sr] = zv.w;
      es[sc*4+0][sr      ] = ev0.x; es[sc*4+1][sr      ] = ev0.y;
      es[sc*4+2][sr      ] = ev0.z; es[sc*4+3][sr      ] = ev0.w;
      es[sc*4+0][sr +  64] = ev1.x; es[sc*4+1][sr +  64] = ev1.y;
      es[sc*4+2][sr +  64] = ev1.z; es[sc*4+3][sr +  64] = ev1.w;
      es[sc*4+0][sr + 128] = ev2.x; es[sc*4+1][sr + 128] = ev2.y;
      es[sc*4+2][sr + 128] = ev2.z; es[sc*4+3][sr + 128] = ev2.w;
      es[sc*4+0][sr + 192] = ev3.x; es[sc*4+1][sr + 192] = ev3.y;
      es[sc*4+2][sr + 192] = ev3.z; es[sc*4+3][sr + 192] = ev3.w;
      __syncthreads();
      #pragma unroll
      for (int k = 0; k < 16; ++k) {
        float4 za0 = *(const float4*)&zs[k][ty * 8];
        float4 za1 = *(const float4*)&zs[k][ty * 8 + 4];
        float4 ea0 = *(const float4*)&es[k][tx * 8];
        float4 ea1 = *(const float4*)&es[k][tx * 8 + 4];
        float zr[8] = {za0.x,za0.y,za0.z,za0.w,za1.x,za1.y,za1.z,za1.w};
        float er[8] = {ea0.x,ea0.y,ea0.z,ea0.w,ea1.x,ea1.y,ea1.z,ea1.w};
        #pragma unroll
        for (int i = 0; i < 8; ++i)
          #pragma unroll
          for (int j = 0; j < 8; ++j)
            acc[i][j] = fmaf(zr[i], er[j], acc[i][j]);
      }
    }

    // fold this group's codes into the running per-token argmin (np semantics)
    float en[8];
    #pragma unroll
    for (int j = 0; j < 8; ++j) en[j] = esum[cg * 256 + tx * 8 + j];
    #pragma unroll
    for (int i = 0; i < 8; ++i)
      #pragma unroll
      for (int j = 0; j < 8; ++j) {
        float s = zsr[i] + en[j];            // fl(zsum + esum_j)
        float v = s - 2.f * acc[i][j];       // fl(s - 2*dot) (2*dot exact)
        int idx = cg * 256 + tx * 8 + j;
        if (v < bv1[i] || (v == bv1[i] && idx < bi1[i])) { bv1[i] = v; bi1[i] = idx; }
      }
  }

  // merge across the 32 tx-lanes sharing this ty (disjoint hypercube sets)
  #pragma unroll
  for (int i = 0; i < 8; ++i) {
    float v1 = bv1[i]; int i1 = bi1[i];
    #pragma unroll
    for (int m = 16; m >= 1; m >>= 1) {
      float ov = __shfl_xor(v1, m); int oi = __shfl_xor(i1, m);
      if (ov < v1 || (ov == v1 && oi < i1)) { v1 = ov; i1 = oi; }
    }
    if (tx == 0) {
      int t = tb * 64 + ty * 8 + i;
      idx_final[t] = i1;
      out[IDX_OFF + t] = bfround((float)i1);
      atomicAdd(&counts[i1], 1);
    }
  }
}

// 8 tokens/block, 32 threads/token: write z_q (fp32, bf16-rounded) + loss sum
__global__ __launch_bounds__(256) void gather_loss(
    const float* __restrict__ z, const float* __restrict__ e,
    const int* __restrict__ idx_final, float* __restrict__ out,
    float* __restrict__ loss) {
  int t = blockIdx.x * 8 + (threadIdx.x >> 5);
  int g = threadIdx.x & 31;
  int idx = idx_final[t] & (NE - 1);   // structurally in-bounds
  const float* zr = z + (size_t)t * DIM;
  const float* er = e + (size_t)idx * DIM;
  float* op = out + (size_t)t * DIM;
  float s = 0.f;
  #pragma unroll
  for (int p = 0; p < 4; ++p) {
    int c = p * 128 + g * 4;
    float4 ev = *(const float4*)(er + c);
    float4 zv = *(const float4*)(zr + c);
    float4 ov;
    ov.x = bfround(ev.x); ov.y = bfround(ev.y);
    ov.z = bfround(ev.z); ov.w = bfround(ev.w);
    *(float4*)(op + c) = ov;
    float dx = ev.x - zv.x, dy = ev.y - zv.y, dz2 = ev.z - zv.z, dw = ev.w - zv.w;
    s += dx*dx + dy*dy + dz2*dz2 + dw*dw;
  }
  #pragma unroll
  for (int m = 32; m >= 1; m >>= 1) s += __shfl_xor(s, m);
  if ((threadIdx.x & 63) == 0) atomicAdd(loss, s);
}

__global__ void finalize_kernel(const int* __restrict__ counts,
                                const float* __restrict__ loss,
                                float* __restrict__ out) {
  __shared__ float red[4];
  int tid = threadIdx.x;
  float s = 0.f;
  for (int j = tid; j < NE; j += 256) {
    float p = (float)counts[j] * (1.0f / (float)N_TOK);
    s += p * logf(p + 1e-10f);
  }
  #pragma unroll
  for (int m = 32; m >= 1; m >>= 1) s += __shfl_xor(s, m);
  if ((tid & 63) == 0) red[tid >> 6] = s;
  __syncthreads();
  if (tid == 0) {
    float tot = red[0] + red[1] + red[2] + red[3];
    out[PERP_OFF] = bfround(expf(-tot));
    out[LOSS_OFF] = bfround(loss[0] * 1.25f / (float)(N_TOK * DIM));
  }
}

extern "C" void kernel_launch(void* const* d_in, const int* in_sizes, int n_in,
                              void* d_out, int out_size, void* d_ws, size_t ws_size,
                              hipStream_t stream) {
  const float* z = (const float*)d_in[0];
  const float* e = (const float*)d_in[1];
  float* out = (float*)d_out;
  char* ws = (char*)d_ws;

  float* zsum      = (float*)(ws + KB(0));     // 128 KB
  float* esum      = (float*)(ws + KB(128));   // 8 KB
  int*   counts    = (int*)  (ws + KB(136));   // 8 KB
  float* loss      = (float*)(ws + KB(144));   // 4 B
  int*   idx_final = (int*)  (ws + KB(148));   // 128 KB (ends ~276 KB)

  init_kernel<<<1, 256, 0, stream>>>(counts, loss);
  npsum_sq<<<N_TOK / 16, 256, 0, stream>>>(z, zsum, N_TOK);
  npsum_sq<<<NE / 16, 256, 0, stream>>>(e, esum, NE);
  dist_topk<<<N_TOK / 64, 256, 0, stream>>>(z, e, zsum, esum, idx_final, counts, out);
  gather_loss<<<N_TOK / 8, 256, 0, stream>>>(z, e, idx_final, out, loss);
  finalize_kernel<<<1, 256, 0, stream>>>(counts, loss, out);
}

// Round 5
// 1131.521 us; speedup vs baseline: 1.0054x; 1.0054x over previous
//
#include <hip/hip_runtime.h>
#include <hip/hip_bf16.h>

#define N_TOK 32768
#define DIM   512
#define NE    2048

// d_out is FLOAT32, outputs concatenated flat in return order:
// z_q_st [N_TOK*DIM] | indices [N_TOK] | loss [1] | perplexity [1]
#define IDX_OFF  (N_TOK * DIM)        // 16777216
#define LOSS_OFF (IDX_OFF + N_TOK)    // 16809984
#define PERP_OFF (LOSS_OFF + 1)

#define KB(x) ((size_t)(x) << 10)

typedef float v2f __attribute__((ext_vector_type(2)));

__device__ inline unsigned short f2bf(float f) {
  unsigned int x = __float_as_uint(f);
  x = x + 0x7fffu + ((x >> 16) & 1u);   // round-to-nearest-even
  return (unsigned short)(x >> 16);
}
__device__ inline float bfround(float f) {
  return __uint_as_float((unsigned int)f2bf(f) << 16);
}

__global__ void init_kernel(int* counts, float* loss) {
  int t = threadIdx.x;
  for (int i = t; i < NE; i += 256) counts[i] = 0;
  if (t == 0) *loss = 0.f;
}

// np.sum(x*x, axis=1), numpy pairwise+AVX512 replication (validated round 4).
__global__ __launch_bounds__(256) void npsum_sq(const float* __restrict__ x,
                                                float* __restrict__ out, int nrows) {
#pragma clang fp contract(off)
  int wave = threadIdx.x >> 6;
  int lane = threadIdx.x & 63;
  int grp = lane >> 4, l = lane & 15;
  int row = blockIdx.x * 16 + wave * 4 + grp;
  if (row >= nrows) return;
  const float* a = x + (size_t)row * DIM;
  float L[4];
  #pragma unroll
  for (int b = 0; b < 4; ++b) {
    const float* p = a + b * 128 + l;
    float q[8];
    #pragma unroll
    for (int j = 0; j < 8; ++j) {
      float t = p[16 * j];
      float s = t * t;
      asm volatile("" : "+v"(s));
      q[j] = s;
    }
    float v = ((q[0] + q[1]) + (q[2] + q[3])) + ((q[4] + q[5]) + (q[6] + q[7]));
    v += __shfl_xor(v, 8);
    v += __shfl_xor(v, 4);
    v += __shfl_xor(v, 2);
    v += __shfl_xor(v, 1);
    L[b] = v;
  }
  if (l == 0) out[row] = (L[0] + L[1]) + (L[2] + L[3]);
}

// Block = 64 tokens x 1024 codes (one half; 4 groups of 256). Grid (512, 2).
// Packed-fp32 FMA (v_pk_fma_f32) on independent per-code chains: numerics
// identical to round-4 (sequential-k fmaf per code).
// es slots XOR-swizzled so lane float4 reads spread across all 8 bank groups.
__global__ __launch_bounds__(256, 4) void dist_topk(
    const float* __restrict__ z, const float* __restrict__ e,
    const float* __restrict__ zsum, const float* __restrict__ esum,
    float* __restrict__ vh, int* __restrict__ ih) {
  __shared__ float zs[16][64];     // [k][token]
  __shared__ float es[16 * 256];   // [k][swizzled code slots]
  const int tid = threadIdx.x;
  const int tb = blockIdx.x, hb = blockIdx.y;
  const int tx = tid & 31, ty = tid >> 5;
  const int sr = tid >> 2, sc = tid & 3;

  // swizzled float-offsets of this lane's two float4 slots within an es row
  const int p0 = (((2 * tx)     ^ ((tx >> 3) & 3)) << 2);
  const int p1 = (((2 * tx + 1) ^ ((tx >> 3) & 3)) << 2);
  // swizzled float-offsets for staging writes: code c -> phys float index
  // phys4(c) = (c>>2) ^ ((c>>6)&3); float = phys4*4 + (c&3)
  int wp[4];
  #pragma unroll
  for (int m = 0; m < 4; ++m) {
    int c = sr + 64 * m;
    wp[m] = ((((c >> 2) ^ ((c >> 6) & 3)) << 2) | (c & 3));
  }

  float bv[8]; int bi[8];
  #pragma unroll
  for (int i = 0; i < 8; ++i) { bv[i] = 3.402823466e38f; bi[i] = 0x7fffffff; }

  float zsr[8];
  #pragma unroll
  for (int i = 0; i < 8; ++i) zsr[i] = zsum[tb * 64 + ty * 8 + i];

  const float* zp = z + (size_t)(tb * 64 + sr) * DIM + sc * 4;

  for (int cg = 0; cg < 4; ++cg) {
    const int cgbase = hb * 1024 + cg * 256;
    v2f acc[8][4];
    #pragma unroll
    for (int i = 0; i < 8; ++i)
      #pragma unroll
      for (int j = 0; j < 4; ++j) acc[i][j] = (v2f)(0.f);

    const float* ep = e + (size_t)(cgbase + sr) * DIM + sc * 4;

    for (int kt = 0; kt < DIM / 16; ++kt) {
      float4 zv  = *(const float4*)(zp + kt * 16);
      float4 ev0 = *(const float4*)(ep + kt * 16);
      float4 ev1 = *(const float4*)(ep + (size_t) 64 * DIM + kt * 16);
      float4 ev2 = *(const float4*)(ep + (size_t)128 * DIM + kt * 16);
      float4 ev3 = *(const float4*)(ep + (size_t)192 * DIM + kt * 16);
      __syncthreads();
      zs[sc*4+0][sr] = zv.x; zs[sc*4+1][sr] = zv.y;
      zs[sc*4+2][sr] = zv.z; zs[sc*4+3][sr] = zv.w;
      es[(sc*4+0)*256 + wp[0]] = ev0.x; es[(sc*4+1)*256 + wp[0]] = ev0.y;
      es[(sc*4+2)*256 + wp[0]] = ev0.z; es[(sc*4+3)*256 + wp[0]] = ev0.w;
      es[(sc*4+0)*256 + wp[1]] = ev1.x; es[(sc*4+1)*256 + wp[1]] = ev1.y;
      es[(sc*4+2)*256 + wp[1]] = ev1.z; es[(sc*4+3)*256 + wp[1]] = ev1.w;
      es[(sc*4+0)*256 + wp[2]] = ev2.x; es[(sc*4+1)*256 + wp[2]] = ev2.y;
      es[(sc*4+2)*256 + wp[2]] = ev2.z; es[(sc*4+3)*256 + wp[2]] = ev2.w;
      es[(sc*4+0)*256 + wp[3]] = ev3.x; es[(sc*4+1)*256 + wp[3]] = ev3.y;
      es[(sc*4+2)*256 + wp[3]] = ev3.z; es[(sc*4+3)*256 + wp[3]] = ev3.w;
      __syncthreads();
      #pragma unroll
      for (int k = 0; k < 16; ++k) {
        float4 za0 = *(const float4*)&zs[k][ty * 8];
        float4 za1 = *(const float4*)&zs[k][ty * 8 + 4];
        float4 ea0 = *(const float4*)&es[k * 256 + p0];
        float4 ea1 = *(const float4*)&es[k * 256 + p1];
        float zr[8] = {za0.x,za0.y,za0.z,za0.w,za1.x,za1.y,za1.z,za1.w};
        v2f e2[4];
        e2[0] = (v2f){ea0.x, ea0.y}; e2[1] = (v2f){ea0.z, ea0.w};
        e2[2] = (v2f){ea1.x, ea1.y}; e2[3] = (v2f){ea1.z, ea1.w};
        #pragma unroll
        for (int i = 0; i < 8; ++i) {
          v2f z2 = (v2f){zr[i], zr[i]};
          #pragma unroll
          for (int j = 0; j < 4; ++j)
            acc[i][j] = __builtin_elementwise_fma(z2, e2[j], acc[i][j]);
        }
      }
    }

    // fold into running argmin with np fp32 semantics (first-index ties)
    float en[8];
    #pragma unroll
    for (int j = 0; j < 8; ++j) en[j] = esum[cgbase + tx * 8 + j];
    #pragma unroll
    for (int i = 0; i < 8; ++i) {
      #pragma unroll
      for (int j = 0; j < 4; ++j) {
        {
          float s = zsr[i] + en[2*j];
          float v = s - 2.f * acc[i][j].x;
          int idx = cgbase + tx * 8 + 2*j;
          if (v < bv[i] || (v == bv[i] && idx < bi[i])) { bv[i] = v; bi[i] = idx; }
        }
        {
          float s = zsr[i] + en[2*j+1];
          float v = s - 2.f * acc[i][j].y;
          int idx = cgbase + tx * 8 + 2*j + 1;
          if (v < bv[i] || (v == bv[i] && idx < bi[i])) { bv[i] = v; bi[i] = idx; }
        }
      }
    }
  }

  // merge across the 32 tx-lanes sharing this ty (disjoint code sets)
  #pragma unroll
  for (int i = 0; i < 8; ++i) {
    float v1 = bv[i]; int i1 = bi[i];
    #pragma unroll
    for (int m = 16; m >= 1; m >>= 1) {
      float ov = __shfl_xor(v1, m); int oi = __shfl_xor(i1, m);
      if (ov < v1 || (ov == v1 && oi < i1)) { v1 = ov; i1 = oi; }
    }
    if (tx == 0) {
      int t = tb * 64 + ty * 8 + i;
      vh[(size_t)hb * N_TOK + t] = v1;
      ih[(size_t)hb * N_TOK + t] = i1;
    }
  }
}

// Merge the two code-halves (half-0 indices < half-1 indices, so <= keeps np
// first-index tie semantics), emit idx / counts / index output.
__global__ __launch_bounds__(256) void merge_halves(
    const float* __restrict__ vh, const int* __restrict__ ih,
    int* __restrict__ idx_final, int* __restrict__ counts,
    float* __restrict__ out) {
  int t = blockIdx.x * 256 + threadIdx.x;
  float v0 = vh[t], v1 = vh[N_TOK + t];
  int i0 = ih[t], i1 = ih[N_TOK + t];
  int w = (v0 <= v1) ? i0 : i1;
  idx_final[t] = w;
  out[IDX_OFF + t] = bfround((float)w);
  atomicAdd(&counts[w], 1);
}

// 8 tokens/block, 32 threads/token: write z_q (fp32, bf16-rounded) + loss sum
__global__ __launch_bounds__(256) void gather_loss(
    const float* __restrict__ z, const float* __restrict__ e,
    const int* __restrict__ idx_final, float* __restrict__ out,
    float* __restrict__ loss) {
  int t = blockIdx.x * 8 + (threadIdx.x >> 5);
  int g = threadIdx.x & 31;
  int idx = idx_final[t] & (NE - 1);   // structurally in-bounds
  const float* zr = z + (size_t)t * DIM;
  const float* er = e + (size_t)idx * DIM;
  float* op = out + (size_t)t * DIM;
  float s = 0.f;
  #pragma unroll
  for (int p = 0; p < 4; ++p) {
    int c = p * 128 + g * 4;
    float4 ev = *(const float4*)(er + c);
    float4 zv = *(const float4*)(zr + c);
    float4 ov;
    ov.x = bfround(ev.x); ov.y = bfround(ev.y);
    ov.z = bfround(ev.z); ov.w = bfround(ev.w);
    *(float4*)(op + c) = ov;
    float dx = ev.x - zv.x, dy = ev.y - zv.y, dz2 = ev.z - zv.z, dw = ev.w - zv.w;
    s += dx*dx + dy*dy + dz2*dz2 + dw*dw;
  }
  #pragma unroll
  for (int m = 32; m >= 1; m >>= 1) s += __shfl_xor(s, m);
  if ((threadIdx.x & 63) == 0) atomicAdd(loss, s);
}

__global__ void finalize_kernel(const int* __restrict__ counts,
                                const float* __restrict__ loss,
                                float* __restrict__ out) {
  __shared__ float red[4];
  int tid = threadIdx.x;
  float s = 0.f;
  for (int j = tid; j < NE; j += 256) {
    float p = (float)counts[j] * (1.0f / (float)N_TOK);
    s += p * logf(p + 1e-10f);
  }
  #pragma unroll
  for (int m = 32; m >= 1; m >>= 1) s += __shfl_xor(s, m);
  if ((tid & 63) == 0) red[tid >> 6] = s;
  __syncthreads();
  if (tid == 0) {
    float tot = red[0] + red[1] + red[2] + red[3];
    out[PERP_OFF] = bfround(expf(-tot));
    out[LOSS_OFF] = bfround(loss[0] * 1.25f / (float)(N_TOK * DIM));
  }
}

extern "C" void kernel_launch(void* const* d_in, const int* in_sizes, int n_in,
                              void* d_out, int out_size, void* d_ws, size_t ws_size,
                              hipStream_t stream) {
  const float* z = (const float*)d_in[0];
  const float* e = (const float*)d_in[1];
  float* out = (float*)d_out;
  char* ws = (char*)d_ws;

  float* zsum      = (float*)(ws + KB(0));     // 128 KB
  float* esum      = (float*)(ws + KB(128));   // 8 KB
  int*   counts    = (int*)  (ws + KB(136));   // 8 KB
  float* loss      = (float*)(ws + KB(144));   // 4 B
  int*   idx_final = (int*)  (ws + KB(148));   // 128 KB
  float* vh        = (float*)(ws + KB(276));   // 256 KB (2 halves)
  int*   ih        = (int*)  (ws + KB(532));   // 256 KB (ends ~788 KB)

  init_kernel<<<1, 256, 0, stream>>>(counts, loss);
  npsum_sq<<<N_TOK / 16, 256, 0, stream>>>(z, zsum, N_TOK);
  npsum_sq<<<NE / 16, 256, 0, stream>>>(e, esum, NE);
  dist_topk<<<dim3(N_TOK / 64, 2), 256, 0, stream>>>(z, e, zsum, esum, vh, ih);
  merge_halves<<<N_TOK / 256, 256, 0, stream>>>(vh, ih, idx_final, counts, out);
  gather_loss<<<N_TOK / 8, 256, 0, stream>>>(z, e, idx_final, out, loss);
  finalize_kernel<<<1, 256, 0, stream>>>(counts, loss, out);
}

// Round 6
// 895.264 us; speedup vs baseline: 1.2707x; 1.2639x over previous
//
#include <hip/hip_runtime.h>
#include <hip/hip_bf16.h>

#define N_TOK 32768
#define DIM   512
#define NE    2048

#define IDX_OFF  (N_TOK * DIM)
#define LOSS_OFF (IDX_OFF + N_TOK)
#define PERP_OFF (LOSS_OFF + 1)

#define KB(x) ((size_t)(x) << 10)
#define EPS 4e-4f
#define ENTRY_CAP (1u << 18)

typedef __attribute__((ext_vector_type(8))) short bf16x8;
typedef __attribute__((ext_vector_type(4))) float f32x4;

__device__ inline unsigned short f2bf(float f) {
  unsigned int x = __float_as_uint(f);
  x = x + 0x7fffu + ((x >> 16) & 1u);
  return (unsigned short)(x >> 16);
}
__device__ inline float bfround(float f) {
  return __uint_as_float((unsigned int)f2bf(f) << 16);
}
__device__ inline unsigned ord_enc(float f) {   // orderable-uint encoding
  unsigned b = __float_as_uint(f);
  return (b & 0x80000000u) ? ~b : (b | 0x80000000u);
}
__device__ inline float ord_dec(unsigned u) {
  unsigned b = (u & 0x80000000u) ? (u & 0x7fffffffu) : ~u;
  return __uint_as_float(b);
}

__global__ void init_kernel(int* counts, float* loss,
                            unsigned long long* tokkey, unsigned* cnt) {
  int g = blockIdx.x * 256 + threadIdx.x;
  for (int i = g; i < NE; i += gridDim.x * 256) counts[i] = 0;
  for (int i = g; i < N_TOK; i += gridDim.x * 256) tokkey[i] = 0xFFFFFFFFFFFFFFFFull;
  if (g == 0) { *loss = 0.f; *cnt = 0u; }
}

// np.sum(x*x, axis=1) exact replication (validated round 4) — do not touch.
__global__ __launch_bounds__(256) void npsum_sq(const float* __restrict__ x,
                                                float* __restrict__ out, int nrows) {
#pragma clang fp contract(off)
  int wave = threadIdx.x >> 6;
  int lane = threadIdx.x & 63;
  int grp = lane >> 4, l = lane & 15;
  int row = blockIdx.x * 16 + wave * 4 + grp;
  if (row >= nrows) return;
  const float* a = x + (size_t)row * DIM;
  float L[4];
  #pragma unroll
  for (int b = 0; b < 4; ++b) {
    const float* p = a + b * 128 + l;
    float q[8];
    #pragma unroll
    for (int j = 0; j < 8; ++j) {
      float t = p[16 * j];
      float s = t * t;
      asm volatile("" : "+v"(s));
      q[j] = s;
    }
    float v = ((q[0] + q[1]) + (q[2] + q[3])) + ((q[4] + q[5]) + (q[6] + q[7]));
    v += __shfl_xor(v, 8);
    v += __shfl_xor(v, 4);
    v += __shfl_xor(v, 2);
    v += __shfl_xor(v, 1);
    L[b] = v;
  }
  if (l == 0) out[row] = (L[0] + L[1]) + (L[2] + L[3]);
}

__global__ __launch_bounds__(256) void cvt_e(const float* __restrict__ e,
                                             unsigned short* __restrict__ ebf) {
  int g = (blockIdx.x * 256 + threadIdx.x) * 8;
  float4 a = *(const float4*)(e + g);
  float4 b = *(const float4*)(e + g + 4);
  unsigned short h[8] = {f2bf(a.x), f2bf(a.y), f2bf(a.z), f2bf(a.w),
                         f2bf(b.x), f2bf(b.y), f2bf(b.z), f2bf(b.w)};
  *(uint4*)(ebf + g) = *(uint4*)h;
}

// MFMA bf16 approx-distance GEMM. Block: 128 tokens x 2048 codes (4 panels
// of 512). 512 threads = 8 waves, wave-tile 64x128 (4x8 frags 16x16x32).
// val_ij = esum_j - 2*dot_bf16_ij  (zsum omitted: constant per token).
// MODE 0: per-token global min -> tokmin.  MODE 1: emit (token,code) entries
// with val <= tokmin + EPS (candidate set provably contains np argmin).
template <int MODE>
__global__ __launch_bounds__(512, 2) void gemm_pass(
    const float* __restrict__ z, const unsigned short* __restrict__ ebf,
    const float* __restrict__ esum, float* __restrict__ tokmin,
    unsigned* __restrict__ entries, unsigned* __restrict__ cnt) {
  __shared__ unsigned short As[128 * 40];   // [row][32k + 8 pad]
  __shared__ unsigned short Bs[512 * 40];   // [code][32k + 8 pad]
  __shared__ float esum_s[512];
  __shared__ unsigned minarr[128];
  __shared__ float limarr[128];

  const int tid = threadIdx.x;
  const int tb = blockIdx.x;
  const int w = tid >> 6, l = tid & 63;
  const int wrow = (w & 1) * 64, wcol0 = (w >> 1) * 128;
  const int lr = l & 15, lk = l >> 4;

  if (MODE == 0) { if (tid < 128) minarr[tid] = 0xFFFFFFFFu; }
  else           { if (tid < 128) limarr[tid] = tokmin[tb * 128 + tid] + EPS; }

  float rm[4][4];
  #pragma unroll
  for (int i = 0; i < 4; ++i)
    #pragma unroll
    for (int q = 0; q < 4; ++q) rm[i][q] = 3.402823466e38f;

  const float* zbase = z + ((size_t)(tb * 128 + (tid >> 2))) * DIM + (tid & 3) * 8;
  unsigned short* aw = &As[(tid >> 2) * 40 + (tid & 3) * 8];

  for (int cp = 0; cp < 4; ++cp) {
    __syncthreads();                      // prev epilogue done reading esum_s
    esum_s[tid] = esum[cp * 512 + tid];
    const unsigned short* ebase = ebf + ((size_t)(cp * 512 + tid)) * DIM;

    f32x4 acc[4][8];
    #pragma unroll
    for (int i = 0; i < 4; ++i)
      #pragma unroll
      for (int j = 0; j < 8; ++j) acc[i][j] = (f32x4)(0.f);

    for (int kt = 0; kt < 16; ++kt) {
      const int k0 = kt * 32;
      float4 za = *(const float4*)(zbase + k0);
      float4 zb = *(const float4*)(zbase + k0 + 4);
      uint4 b0 = *(const uint4*)(ebase + k0);
      uint4 b1 = *(const uint4*)(ebase + k0 + 8);
      uint4 b2 = *(const uint4*)(ebase + k0 + 16);
      uint4 b3 = *(const uint4*)(ebase + k0 + 24);
      unsigned short h[8] = {f2bf(za.x), f2bf(za.y), f2bf(za.z), f2bf(za.w),
                             f2bf(zb.x), f2bf(zb.y), f2bf(zb.z), f2bf(zb.w)};
      __syncthreads();                    // everyone done with prev tiles
      *(uint4*)aw = *(uint4*)h;
      unsigned short* bw = &Bs[tid * 40];
      *(uint4*)(bw)      = b0;
      *(uint4*)(bw + 8)  = b1;
      *(uint4*)(bw + 16) = b2;
      *(uint4*)(bw + 24) = b3;
      __syncthreads();

      bf16x8 a[4];
      #pragma unroll
      for (int i = 0; i < 4; ++i)
        a[i] = *(const bf16x8*)&As[(wrow + i * 16 + lr) * 40 + lk * 8];
      #pragma unroll
      for (int j = 0; j < 8; ++j) {
        bf16x8 b = *(const bf16x8*)&Bs[(wcol0 + j * 16 + lr) * 40 + lk * 8];
        #pragma unroll
        for (int i = 0; i < 4; ++i)
          acc[i][j] = __builtin_amdgcn_mfma_f32_16x16x32_bf16(a[i], b, acc[i][j], 0, 0, 0);
      }
    }

    // panel epilogue: C/D layout col=lane&15, row=(lane>>4)*4+reg (m89-verified)
    #pragma unroll
    for (int i = 0; i < 4; ++i)
      #pragma unroll
      for (int j = 0; j < 8; ++j) {
        const int col_l = wcol0 + j * 16 + lr;
        #pragma unroll
        for (int q = 0; q < 4; ++q) {
          float v = fmaf(-2.f, acc[i][j][q], esum_s[col_l]);
          if (MODE == 0) {
            rm[i][q] = fminf(rm[i][q], v);
          } else {
            const int lrow = wrow + i * 16 + lk * 4 + q;
            if (v <= limarr[lrow]) {
              unsigned ent = ((unsigned)(tb * 128 + lrow) << 11) |
                             (unsigned)(cp * 512 + col_l);
              unsigned p = atomicAdd(cnt, 1u);
              if (p < ENTRY_CAP) entries[p] = ent;
            }
          }
        }
      }
  }

  if (MODE == 0) {
    #pragma unroll
    for (int i = 0; i < 4; ++i)
      #pragma unroll
      for (int q = 0; q < 4; ++q) {
        float v = rm[i][q];
        v = fminf(v, __shfl_xor(v, 1));
        v = fminf(v, __shfl_xor(v, 2));
        v = fminf(v, __shfl_xor(v, 4));
        v = fminf(v, __shfl_xor(v, 8));
        if (lr == 0) atomicMin(&minarr[wrow + i * 16 + lk * 4 + q], ord_enc(v));
      }
    __syncthreads();
    if (tid < 128) tokmin[tb * 128 + tid] = ord_dec(minarr[tid]);
  }
}

// Exact np-replica rescan per candidate: d = fl(fl(zsum+esum) - 2*seq_fmaf_dot)
// (the validated round-4 chain). Winner per token via 64-bit key atomicMin:
// key = d_bits<<32 | code  -> min d, tie -> smallest code (np first-index).
__global__ __launch_bounds__(256) void rescan_exact(
    const float* __restrict__ z, const float* __restrict__ e,
    const float* __restrict__ zsum, const float* __restrict__ esum,
    const unsigned* __restrict__ entries, const unsigned* __restrict__ cnt,
    unsigned long long* __restrict__ tokkey) {
  unsigned n = *cnt; if (n > ENTRY_CAP) n = ENTRY_CAP;
  for (unsigned g = blockIdx.x * 256 + threadIdx.x; g < n; g += gridDim.x * 256) {
    unsigned ent = entries[g];
    int t = ent >> 11, c = ent & (NE - 1);
    const float* zr = z + (size_t)t * DIM;
    const float* er = e + (size_t)c * DIM;
    float acc = 0.f;
    for (int k = 0; k < DIM; ++k) acc = fmaf(zr[k], er[k], acc);
    float s = zsum[t] + esum[c];
    float d = s - 2.f * acc;
    unsigned long long key = ((unsigned long long)__float_as_uint(d) << 32) |
                             (unsigned long long)c;
    atomicMin(&tokkey[t], key);
  }
}

__global__ __launch_bounds__(256) void writeout(
    const unsigned long long* __restrict__ tokkey, int* __restrict__ idx_final,
    int* __restrict__ counts, float* __restrict__ out) {
  int t = blockIdx.x * 256 + threadIdx.x;
  int c = (int)(tokkey[t] & (unsigned long long)(NE - 1));
  idx_final[t] = c;
  out[IDX_OFF + t] = bfround((float)c);
  atomicAdd(&counts[c], 1);
}

__global__ __launch_bounds__(256) void gather_loss(
    const float* __restrict__ z, const float* __restrict__ e,
    const int* __restrict__ idx_final, float* __restrict__ out,
    float* __restrict__ loss) {
  int t = blockIdx.x * 8 + (threadIdx.x >> 5);
  int g = threadIdx.x & 31;
  int idx = idx_final[t] & (NE - 1);
  const float* zr = z + (size_t)t * DIM;
  const float* er = e + (size_t)idx * DIM;
  float* op = out + (size_t)t * DIM;
  float s = 0.f;
  #pragma unroll
  for (int p = 0; p < 4; ++p) {
    int c = p * 128 + g * 4;
    float4 ev = *(const float4*)(er + c);
    float4 zv = *(const float4*)(zr + c);
    float4 ov;
    ov.x = bfround(ev.x); ov.y = bfround(ev.y);
    ov.z = bfround(ev.z); ov.w = bfround(ev.w);
    *(float4*)(op + c) = ov;
    float dx = ev.x - zv.x, dy = ev.y - zv.y, dz2 = ev.z - zv.z, dw = ev.w - zv.w;
    s += dx*dx + dy*dy + dz2*dz2 + dw*dw;
  }
  #pragma unroll
  for (int m = 32; m >= 1; m >>= 1) s += __shfl_xor(s, m);
  if ((threadIdx.x & 63) == 0) atomicAdd(loss, s);
}

__global__ void finalize_kernel(const int* __restrict__ counts,
                                const float* __restrict__ loss,
                                float* __restrict__ out) {
  __shared__ float red[4];
  int tid = threadIdx.x;
  float s = 0.f;
  for (int j = tid; j < NE; j += 256) {
    float p = (float)counts[j] * (1.0f / (float)N_TOK);
    s += p * logf(p + 1e-10f);
  }
  #pragma unroll
  for (int m = 32; m >= 1; m >>= 1) s += __shfl_xor(s, m);
  if ((tid & 63) == 0) red[tid >> 6] = s;
  __syncthreads();
  if (tid == 0) {
    float tot = red[0] + red[1] + red[2] + red[3];
    out[PERP_OFF] = bfround(expf(-tot));
    out[LOSS_OFF] = bfround(loss[0] * 1.25f / (float)(N_TOK * DIM));
  }
}

extern "C" void kernel_launch(void* const* d_in, const int* in_sizes, int n_in,
                              void* d_out, int out_size, void* d_ws, size_t ws_size,
                              hipStream_t stream) {
  const float* z = (const float*)d_in[0];
  const float* e = (const float*)d_in[1];
  float* out = (float*)d_out;
  char* ws = (char*)d_ws;

  float*    zsum      = (float*)(ws + KB(0));      // 128 KB
  float*    esum      = (float*)(ws + KB(128));    // 8 KB
  int*      counts    = (int*)(ws + KB(136));      // 8 KB
  float*    loss      = (float*)(ws + KB(144));    // 4 KB pad
  int*      idx_final = (int*)(ws + KB(148));      // 128 KB
  float*    tokmin    = (float*)(ws + KB(276));    // 128 KB
  unsigned long long* tokkey = (unsigned long long*)(ws + KB(404)); // 256 KB
  unsigned* cnt       = (unsigned*)(ws + KB(660)); // 4 KB pad
  unsigned* entries   = (unsigned*)(ws + KB(664)); // 1 MB
  unsigned short* ebf = (unsigned short*)(ws + KB(1688)); // 2 MB -> ~3.7 MB total

  init_kernel<<<64, 256, 0, stream>>>(counts, loss, tokkey, cnt);
  npsum_sq<<<N_TOK / 16, 256, 0, stream>>>(z, zsum, N_TOK);
  npsum_sq<<<NE / 16, 256, 0, stream>>>(e, esum, NE);
  cvt_e<<<(NE * DIM) / (256 * 8), 256, 0, stream>>>(e, ebf);
  gemm_pass<0><<<N_TOK / 128, 512, 0, stream>>>(z, ebf, esum, tokmin, entries, cnt);
  gemm_pass<1><<<N_TOK / 128, 512, 0, stream>>>(z, ebf, esum, tokmin, entries, cnt);
  rescan_exact<<<512, 256, 0, stream>>>(z, e, zsum, esum, entries, cnt, tokkey);
  writeout<<<N_TOK / 256, 256, 0, stream>>>(tokkey, idx_final, counts, out);
  gather_loss<<<N_TOK / 8, 256, 0, stream>>>(z, e, idx_final, out, loss);
  finalize_kernel<<<1, 256, 0, stream>>>(counts, loss, out);
}